// Round 1
// baseline (1298.348 us; speedup 1.0000x reference)
//
#include <hip/hip_runtime.h>
#include <stdint.h>

// Problem constants (from reference): B=8, P=4096, N=1024, H=W=1024
#define PPTS 4096
#define NGT  1024
#define HH   1024
#define WW   1024
#define NLAB 1025   // mask labels in [0, 1024]

// One block per batch. Prologue (1024 threads): stage data, bucket points by
// label. Scan (wave 0 only, barrier-free): 1024 sequential matching steps.
__global__ __launch_bounds__(1024) void matcher_kernel(
    const float* __restrict__ pred,    // [B,P,2]
    const float* __restrict__ coords,  // [B,N,2]
    const int*   __restrict__ keys,    // [B,N]
    const int*   __restrict__ masks,   // [B,H,W]
    float* __restrict__ out,           // [B*N src][B*N tgt][B total]
    int B)
{
    __shared__ float2         ldsU[PPTS];            // 32768 B point coords
    __shared__ unsigned short ldsLab[PPTS];          //  8192 B point labels
    __shared__ unsigned short ldsEnt[PPTS];          //  8192 B bucket entries (point ids)
    __shared__ int            ldsCur[NLAB];          //  4100 B hist -> excl offsets -> bucket ends
    __shared__ unsigned short ldsKey1[NGT];          //  2048 B keys[j]+1
    __shared__ float2         ldsV[NGT];             //  8192 B gt coords
    __shared__ unsigned int   ldsAvail[PPTS / 32];   //   512 B avail bitmask
    __shared__ unsigned int   ldsBg[PPTS / 32];      //   512 B background bitmask
    __shared__ unsigned int   ldsPresent[(NLAB + 31) / 32]; // 132 B label-in-keyset

    const int b = blockIdx.x;
    const int t = threadIdx.x;
    const float* Ub = pred   + (size_t)b * PPTS * 2;
    const float* Vb = coords + (size_t)b * NGT * 2;
    const int*   Kb = keys   + (size_t)b * NGT;
    const int*   Mb = masks  + (size_t)b * HH * WW;

    // ---- phase A: zero LDS state ----
    ldsCur[t] = 0;
    if (t == 0) ldsCur[1024] = 0;
    if (t < PPTS / 32) { ldsAvail[t] = 0; ldsBg[t] = 0; }
    if (t < (NLAB + 31) / 32) ldsPresent[t] = 0;
    __syncthreads();

    // ---- phase B: stage keys/V, load U, compute labels, histogram ----
    {
        int k1 = Kb[t] + 1;                 // key+1 in [1, 1024]
        ldsKey1[t] = (unsigned short)k1;
        atomicOr(&ldsPresent[k1 >> 5], 1u << (k1 & 31));
        ldsV[t] = ((const float2*)Vb)[t];
    }
    for (int p = t; p < PPTS; p += 1024) {
        float2 u = ((const float2*)Ub)[p];
        ldsU[p] = u;
        // labels = lm[clip(rint(ux*H),0,H-1), clip(rint(uy*W),0,W-1)]
        // rintf == round-half-even == jnp.round; no FMA anywhere.
        int xi = (int)rintf(__fmul_rn(u.x, 1024.0f));
        int yi = (int)rintf(__fmul_rn(u.y, 1024.0f));
        xi = min(max(xi, 0), HH - 1);
        yi = min(max(yi, 0), WW - 1);
        int lab = Mb[xi * WW + yi];
        ldsLab[p] = (unsigned short)lab;
        atomicAdd(&ldsCur[lab], 1);
    }
    __syncthreads();

    // ---- phase C: inclusive scan over ldsCur[0..1024], then exclusive shift ----
    for (int stride = 1; stride < NLAB; stride <<= 1) {
        int i1 = t + 1024;
        int v0 = 0, v1 = 0;
        if (t >= stride)               v0 = ldsCur[t - stride];
        if (i1 < NLAB && i1 >= stride) v1 = ldsCur[i1 - stride];
        __syncthreads();
        ldsCur[t] += v0;
        if (i1 < NLAB) ldsCur[i1] += v1;
        __syncthreads();
    }
    {
        int e0 = (t == 0) ? 0 : ldsCur[t - 1];
        int e1 = ldsCur[1023];
        __syncthreads();
        ldsCur[t] = e0;
        if (t == 0) ldsCur[1024] = e1;
        __syncthreads();
    }

    // ---- phase D: scatter into buckets + init avail/bg bitmasks ----
    for (int p = t; p < PPTS; p += 1024) {
        int lab = ldsLab[p];
        int slot = atomicAdd(&ldsCur[lab], 1);   // after this, ldsCur[l] = end of bucket l
        ldsEnt[slot] = (unsigned short)p;
        int inAny = (ldsPresent[lab >> 5] >> (lab & 31)) & 1;
        if (inAny) atomicOr(&ldsAvail[p >> 5], 1u << (p & 31));
        else       atomicOr(&ldsBg[p >> 5],    1u << (p & 31));
    }
    __syncthreads();

    // ---- scan: single wave, no barriers ----
    if (t >= 64) return;
    const int lane = t;
    float total = 0.0f;
    float* outSrc = out + (size_t)b * NGT;
    float* outTgt = out + (size_t)B * NGT + (size_t)b * NGT;

    for (int j = 0; j < NGT; ++j) {
        const int key1 = ldsKey1[j];
        const float vx = ldsV[j].x, vy = ldsV[j].y;
        const int start = ldsCur[key1 - 1];   // end of bucket key1-1 == start of key1
        const int end   = ldsCur[key1];
        const int cnt   = end - start;

        // candidate argmin: packed (dist_bits<<32)|p, min => min dist, first index
        unsigned long long best = ~0ULL;
        for (int base = 0; base < cnt; base += 64) {
            int k = base + lane;
            if (k < cnt) {
                int p = ldsEnt[start + k];
                if ((ldsAvail[p >> 5] >> (p & 31)) & 1u) {
                    float2 u = ldsU[p];
                    float dx = __fsub_rn(vx, u.x);
                    float dy = __fsub_rn(vy, u.y);
                    float d = __fsqrt_rn(__fadd_rn(__fmul_rn(dx, dx), __fmul_rn(dy, dy)));
                    unsigned long long pk =
                        ((unsigned long long)__float_as_uint(d) << 32) | (unsigned)p;
                    if (pk < best) best = pk;
                }
            }
        }
        #pragma unroll
        for (int off = 32; off >= 1; off >>= 1) {
            unsigned long long o = __shfl_xor(best, off, 64);
            if (o < best) best = o;
        }

        int u;
        float cost;
        if (best != ~0ULL) {
            // inside match: remove winner from avail, dump other candidates into bg
            u = (int)(best & 0xFFFFFFFFu);
            cost = __uint_as_float((unsigned)(best >> 32));
            for (int base = 0; base < cnt; base += 64) {
                int k = base + lane;
                if (k < cnt) {
                    int p = ldsEnt[start + k];
                    if (p != u && ((ldsAvail[p >> 5] >> (p & 31)) & 1u))
                        atomicOr(&ldsBg[p >> 5], 1u << (p & 31));
                }
            }
            if (lane == 0) atomicAnd(&ldsAvail[u >> 5], ~(1u << (u & 31)));
        } else {
            // background match: full scan of bg bitmask (rare, ~2% of steps)
            best = ~0ULL;
            unsigned w0 = ldsBg[2 * lane];
            unsigned w1 = ldsBg[2 * lane + 1];
            unsigned long long bits = ((unsigned long long)w1 << 32) | w0;
            const int pbase = lane << 6;
            while (bits) {
                int bpos = __builtin_ctzll(bits);
                bits &= bits - 1;
                int p = pbase + bpos;
                float2 u2 = ldsU[p];
                float dx = __fsub_rn(vx, u2.x);
                float dy = __fsub_rn(vy, u2.y);
                float d = __fsqrt_rn(__fadd_rn(__fmul_rn(dx, dx), __fmul_rn(dy, dy)));
                unsigned long long pk =
                    ((unsigned long long)__float_as_uint(d) << 32) | (unsigned)p;
                if (pk < best) best = pk;
            }
            #pragma unroll
            for (int off = 32; off >= 1; off >>= 1) {
                unsigned long long o = __shfl_xor(best, off, 64);
                if (o < best) best = o;
            }
            if (best != ~0ULL) {
                u = (int)(best & 0xFFFFFFFFu);
                cost = __uint_as_float((unsigned)(best >> 32));
                if (lane == 0) atomicAnd(&ldsBg[u >> 5], ~(1u << (u & 31)));
            } else {
                u = -1;
                cost = 0.0f;
            }
        }
        __threadfence_block();   // make avail/bg updates visible before next iteration
        if (lane == 0) {
            outSrc[j] = (float)u;
            outTgt[j] = (u >= 0) ? (float)j : -1.0f;
            total = __fadd_rn(total, cost);   // sequential like the scan; tolerance covers
        }
    }
    if (lane == 0) out[(size_t)2 * B * NGT + b] = total;
}

extern "C" void kernel_launch(void* const* d_in, const int* in_sizes, int n_in,
                              void* d_out, int out_size, void* d_ws, size_t ws_size,
                              hipStream_t stream) {
    const float* pred   = (const float*)d_in[0];
    const float* coords = (const float*)d_in[1];
    const int*   keys   = (const int*)d_in[2];
    const int*   masks  = (const int*)d_in[3];
    float* out = (float*)d_out;
    int B = in_sizes[2] / NGT;   // 8
    matcher_kernel<<<B, 1024, 0, stream>>>(pred, coords, keys, masks, out, B);
}

// Round 2
// 522.228 us; speedup vs baseline: 2.4862x; 2.4862x over previous
//
#include <hip/hip_runtime.h>
#include <stdint.h>

// Problem constants: B=8, P=4096, N=1024, H=W=1024, labels 0..1024
#define PPTS 4096
#define NGT  1024
#define HH   1024
#define WW   1024

__device__ __forceinline__ float pdist(float vx, float vy, float ux, float uy) {
    float dx = __fsub_rn(vx, ux);
    float dy = __fsub_rn(vy, uy);
    return __fsqrt_rn(__fadd_rn(__fmul_rn(dx, dx), __fmul_rn(dy, dy)));
}

// One block per batch.
// Phase A-D: stage U, label points, counting-sort into per-label buckets,
//            per-label key-occurrence lists, bg0 bitmask.
// Phase 1a:  one THREAD per label runs that label's inside-match chain
//            (avail evolution is label-local) -> matchU[j], event counts.
// Phase 1b:  replay to emit bg-add events (dumped candidates) into global ws,
//            j-sorted via prefix-scanned offsets.
// Phase 2:   single wave walks the ~dozens of exhausted steps in j order:
//            apply events with j < j*, packed-argmin over bg bitmask, remove
//            winner. Exact reproduction of the reference interleaving.
__global__ __launch_bounds__(1024) void matcher_kernel(
    const float* __restrict__ pred,    // [B,P,2]
    const float* __restrict__ coords,  // [B,N,2]
    const int*   __restrict__ keys,    // [B,N]
    const int*   __restrict__ masks,   // [B,H,W]
    float* __restrict__ out,           // [B*N src][B*N tgt][B total]
    unsigned* __restrict__ evGlobAll, int evCap, int B)
{
    __shared__ float2         ldsU[PPTS];          // 32768
    __shared__ unsigned short ldsEnt[PPTS];        //  8192 bucket entries
    __shared__ int            bEnd[1025];          //  4100 bucket offsets/ends
    __shared__ int            occA[1025];          //  4100 key-occurrence offsets
    __shared__ int            evA[1025];           //  4100 event offsets by step
    __shared__ unsigned short occList[NGT];        //  2048 j's grouped by label
    __shared__ short          matchU[NGT];         //  2048 result per step
    __shared__ unsigned       consumed[PPTS / 32]; //   512
    __shared__ unsigned       bgbits[PPTS / 32];   //   512
    __shared__ unsigned       present[33];         //   132
    __shared__ float          waveCost[16];        //    64   (total ~58.6 KB)

    const int b = blockIdx.x;
    const int t = threadIdx.x;
    const float* Ub = pred   + (size_t)b * PPTS * 2;
    const float* Vb = coords + (size_t)b * NGT * 2;
    const int*   Kb = keys   + (size_t)b * NGT;
    const int*   Mb = masks  + (size_t)b * HH * WW;
    unsigned* evGlob = evGlobAll + (size_t)b * (size_t)evCap;

    // ---- A: zero ----
    bEnd[t] = 0; occA[t] = 0; evA[t] = 0;
    if (t == 0) { bEnd[1024] = 0; occA[1024] = 0; evA[1024] = 0; }
    if (t < PPTS / 32) { consumed[t] = 0; bgbits[t] = 0; }
    if (t < 33) present[t] = 0;
    __syncthreads();

    // ---- B: histograms ----
    const int k1 = Kb[t] + 1;                    // label of step j=t, in [1,1024]
    atomicOr(&present[k1 >> 5], 1u << (k1 & 31));
    atomicAdd(&occA[k1], 1);
    int lab[4];
    #pragma unroll
    for (int i = 0; i < 4; i++) {
        int p = t + i * 1024;
        float2 u = ((const float2*)Ub)[p];
        ldsU[p] = u;
        int xi = (int)rintf(__fmul_rn(u.x, 1024.0f));  // rintf == jnp.round (half-even)
        int yi = (int)rintf(__fmul_rn(u.y, 1024.0f));
        xi = min(max(xi, 0), HH - 1);
        yi = min(max(yi, 0), WW - 1);
        lab[i] = Mb[xi * WW + yi];
        atomicAdd(&bEnd[lab[i]], 1);
    }
    __syncthreads();

    // ---- C: joint inclusive scan of bEnd & occA (1025 each), shift to exclusive ----
    for (int stride = 1; stride < 1025; stride <<= 1) {
        int i1 = t + 1024;
        int a0 = 0, a1 = 0, c0 = 0, c1 = 0;
        if (t >= stride)               { a0 = bEnd[t - stride];  c0 = occA[t - stride]; }
        if (i1 < 1025 && i1 >= stride) { a1 = bEnd[i1 - stride]; c1 = occA[i1 - stride]; }
        __syncthreads();
        bEnd[t] += a0; occA[t] += c0;
        if (i1 < 1025) { bEnd[i1] += a1; occA[i1] += c1; }
        __syncthreads();
    }
    {
        int eA = (t == 0) ? 0 : bEnd[t - 1];
        int eB = (t == 0) ? 0 : occA[t - 1];
        int tA = bEnd[1023], tB = occA[1023];
        __syncthreads();
        bEnd[t] = eA; occA[t] = eB;
        if (t == 0) { bEnd[1024] = tA; occA[1024] = tB; }
        __syncthreads();
    }

    // ---- D: scatter (starts -> ends via atomicAdd), bg0 init ----
    #pragma unroll
    for (int i = 0; i < 4; i++) {
        int p = t + i * 1024;
        int slot = atomicAdd(&bEnd[lab[i]], 1);
        ldsEnt[slot] = (unsigned short)p;
        if (!((present[lab[i] >> 5] >> (lab[i] & 31)) & 1u))
            atomicOr(&bgbits[p >> 5], 1u << (p & 31));
    }
    {
        int slot = atomicAdd(&occA[k1], 1);
        occList[slot] = (unsigned short)t;    // j = t
    }
    __syncthreads();

    // ---- 1a: per-label inside-match chains (thread t handles label t+1) ----
    float costPartial = 0.0f;
    {
        const int l = t + 1;
        const int os = occA[l - 1], oe = occA[l];
        // sort this label's occurrence list ascending (few elements)
        for (int i = os + 1; i < oe; i++) {
            unsigned short v = occList[i];
            int k = i - 1;
            while (k >= os && occList[k] > v) { occList[k + 1] = occList[k]; k--; }
            occList[k + 1] = v;
        }
        const int bs = bEnd[l - 1], be = bEnd[l];
        for (int o = os; o < oe; o++) {
            int j = occList[o];
            float2 v = ((const float2*)Vb)[j];
            unsigned long long best = ~0ULL;
            int availCnt = 0;
            for (int e = bs; e < be; e++) {
                int p = ldsEnt[e];
                if ((consumed[p >> 5] >> (p & 31)) & 1u) continue;
                availCnt++;
                float d = pdist(v.x, v.y, ldsU[p].x, ldsU[p].y);
                unsigned long long pk =
                    ((unsigned long long)__float_as_uint(d) << 32) | (unsigned)p;
                if (pk < best) best = pk;
            }
            if (availCnt > 0) {
                int u = (int)(best & 0xFFFFFFFFu);
                costPartial = __fadd_rn(costPartial, __uint_as_float((unsigned)(best >> 32)));
                matchU[j] = (short)u;
                atomicOr(&consumed[u >> 5], 1u << (u & 31));
                evA[j + 1] = availCnt - 1;     // dump count for this step
            } else {
                matchU[j] = -2;                // needs background match
            }
        }
    }
    __syncthreads();

    // ---- event-offset scan (evA inclusive: evA[j] = #events of steps < j) ----
    if (t < PPTS / 32) consumed[t] = 0;        // reset for replay
    for (int stride = 1; stride < 1025; stride <<= 1) {
        int i1 = t + 1024;
        int a0 = 0, a1 = 0;
        if (t >= stride)               a0 = evA[t - stride];
        if (i1 < 1025 && i1 >= stride) a1 = evA[i1 - stride];
        __syncthreads();
        evA[t] += a0;
        if (i1 < 1025) evA[i1] += a1;
        __syncthreads();
    }

    // ---- 1b: replay consumption, emit bg-add events (j-sorted by construction) ----
    {
        const int l = t + 1;
        const int os = occA[l - 1], oe = occA[l];
        const int bs = bEnd[l - 1], be = bEnd[l];
        for (int o = os; o < oe; o++) {
            int j = occList[o];
            int u = matchU[j];
            if (u < 0) continue;
            int w = evA[j];
            for (int e = bs; e < be; e++) {
                int p = ldsEnt[e];
                if ((consumed[p >> 5] >> (p & 31)) & 1u) continue;
                if (p != u) {
                    if (w < evCap) evGlob[w] = (unsigned)p;
                    w++;
                }
            }
            atomicOr(&consumed[u >> 5], 1u << (u & 31));
        }
    }
    __threadfence_block();
    __syncthreads();

    // ---- 2: single wave, bg-matches in j order ----
    float bgCost = 0.0f;
    if (t < 64) {
        const int lane = t;
        int applied = 0;
        for (int c = 0; c < 16; c++) {
            short mu = matchU[c * 64 + lane];
            unsigned long long need = __ballot(mu == (short)-2);
            while (need) {
                int bit = __builtin_ctzll(need);
                need &= need - 1;
                const int js = c * 64 + bit;
                // apply all bg-add events from steps < js
                const int target = evA[js];
                while (applied < target) {
                    int idx = applied + lane;
                    if (idx < target && idx < evCap) {
                        unsigned p = evGlob[idx];
                        atomicOr(&bgbits[p >> 5], 1u << (p & 31));
                    }
                    applied = min(applied + 64, target);
                }
                __threadfence_block();
                // packed argmin over bg set
                float2 v = ((const float2*)Vb)[js];
                unsigned w0 = bgbits[2 * lane], w1 = bgbits[2 * lane + 1];
                unsigned long long bits = ((unsigned long long)w1 << 32) | w0;
                const int pbase = lane << 6;
                unsigned long long best = ~0ULL;
                while (bits) {
                    int bp = __builtin_ctzll(bits);
                    bits &= bits - 1;
                    int p = pbase + bp;
                    float d = pdist(v.x, v.y, ldsU[p].x, ldsU[p].y);
                    unsigned long long pk =
                        ((unsigned long long)__float_as_uint(d) << 32) | (unsigned)p;
                    if (pk < best) best = pk;
                }
                #pragma unroll
                for (int off = 32; off >= 1; off >>= 1) {
                    unsigned long long o = __shfl_xor(best, off, 64);
                    if (o < best) best = o;
                }
                if (best != ~0ULL) {
                    int u = (int)(best & 0xFFFFFFFFu);
                    if (lane == 0) {
                        matchU[js] = (short)u;
                        atomicAnd(&bgbits[u >> 5], ~(1u << (u & 31)));
                        bgCost = __fadd_rn(bgCost, __uint_as_float((unsigned)(best >> 32)));
                    }
                } else {
                    if (lane == 0) matchU[js] = -1;
                }
                __threadfence_block();
            }
        }
    }
    __syncthreads();

    // ---- epilogue: cost reduction + outputs ----
    float cp = costPartial;
    #pragma unroll
    for (int off = 32; off >= 1; off >>= 1) cp += __shfl_xor(cp, off, 64);
    if ((t & 63) == 0) waveCost[t >> 6] = cp;
    __syncthreads();
    if (t == 0) {
        float tot = bgCost;
        for (int i = 0; i < 16; i++) tot = __fadd_rn(tot, waveCost[i]);
        out[(size_t)2 * B * NGT + b] = tot;
    }
    {
        int u = matchU[t];
        out[(size_t)b * NGT + t] = (float)u;
        out[(size_t)B * NGT + (size_t)b * NGT + t] = (u >= 0) ? (float)t : -1.0f;
    }
}

extern "C" void kernel_launch(void* const* d_in, const int* in_sizes, int n_in,
                              void* d_out, int out_size, void* d_ws, size_t ws_size,
                              hipStream_t stream) {
    const float* pred   = (const float*)d_in[0];
    const float* coords = (const float*)d_in[1];
    const int*   keys   = (const int*)d_in[2];
    const int*   masks  = (const int*)d_in[3];
    float* out = (float*)d_out;
    int B = in_sizes[2] / NGT;   // 8
    int evCap = (int)((ws_size / (size_t)B) / sizeof(unsigned));
    matcher_kernel<<<B, 1024, 0, stream>>>(pred, coords, keys, masks, out,
                                           (unsigned*)d_ws, evCap, B);
}

// Round 3
// 233.425 us; speedup vs baseline: 5.5622x; 2.2372x over previous
//
#include <hip/hip_runtime.h>
#include <stdint.h>

// Problem constants: B=8, P=4096, N=1024, H=W=1024, labels 0..1024
#define PPTS 4096
#define NGT  1024
#define HH   1024
#define WW   1024
#define EVCAP_LDS 10240   // LDS event pool entries (E[total dumps] ~ 2600)
#define BGCAP 256         // max bg steps tracked (E ~ 68)

typedef unsigned long long u64;

__device__ __forceinline__ float pdist(float vx, float vy, float ux, float uy) {
    float dx = __fsub_rn(vx, ux);
    float dy = __fsub_rn(vy, uy);
    return __fsqrt_rn(__fadd_rn(__fmul_rn(dx, dx), __fmul_rn(dy, dy)));
}

// One block per batch.
//  A-D : stage, label points (mask gather), counting-sort into per-label
//        buckets (ids + coords contiguous), key-occurrence lists, bg0 bitmask.
//  1a  : one THREAD per label runs that label's inside-match chain (avail is
//        label-local); consumed tracked in a register u64 (+ exact fallback).
//  1b  : replay, emit dump events j-sorted into LDS pool (aliased on bucketU).
//  2   : bg steps, FULL BLOCK per step: each thread owns 4 points in regs,
//        eligibility from bgbits, per-wave u64 butterfly, wave0 finalizes.
__global__ __launch_bounds__(1024) void matcher_kernel(
    const float* __restrict__ pred,    // [B,P,2]
    const float* __restrict__ coords,  // [B,N,2]
    const int*   __restrict__ keys,    // [B,N]
    const int*   __restrict__ masks,   // [B,H,W]
    float* __restrict__ out,           // [B*N src][B*N tgt][B total]
    unsigned short* __restrict__ evGlobAll, int evCapG, int B)
{
    __shared__ __align__(16) char poolRaw[32768]; // bucketU (1a) -> evPool+ldsV (2)
    __shared__ unsigned short ldsEnt[PPTS];       //  8192 bucket entry point-ids
    __shared__ int            bEnd[1025];         //  4100
    __shared__ int            occA[1025];         //  4100
    __shared__ int            evA[1025];          //  4100
    __shared__ unsigned short occList[NGT];       //  2048
    __shared__ short          matchU[NGT];        //  2048
    __shared__ unsigned       bgbits[PPTS / 32];  //   512
    __shared__ unsigned       present[33];        //   132
    __shared__ unsigned short bgList[BGCAP];      //   512
    __shared__ int            bgCntSh;
    __shared__ int            waveBase[16];
    __shared__ u64            waveMin[16];
    __shared__ float          waveCost[16];

    float2* bucketU = (float2*)poolRaw;                       // phase 1a
    unsigned short* evPool = (unsigned short*)poolRaw;        // phase 1b/2
    float2* ldsV = (float2*)(poolRaw + 2 * EVCAP_LDS);        // phase 2

    const int b = blockIdx.x;
    const int t = threadIdx.x;
    const float* Ub = pred   + (size_t)b * PPTS * 2;
    const float* Vb = coords + (size_t)b * NGT * 2;
    const int*   Kb = keys   + (size_t)b * NGT;
    const int*   Mb = masks  + (size_t)b * HH * WW;
    unsigned short* evGlobB = evGlobAll + (size_t)b * (size_t)evCapG;

    // ---- A: zero ----
    bEnd[t] = 0; occA[t] = 0; evA[t] = 0;
    if (t == 0) { bEnd[1024] = 0; occA[1024] = 0; evA[1024] = 0; bgCntSh = 0; }
    if (t < PPTS / 32) bgbits[t] = 0;
    if (t < 33) present[t] = 0;
    __syncthreads();

    // ---- B: histograms + mask gather; coords of owned points stay in regs ----
    const int k1 = Kb[t] + 1;                     // label of step j=t, in [1,1024]
    atomicOr(&present[k1 >> 5], 1u << (k1 & 31));
    atomicAdd(&occA[k1], 1);
    int lab[4]; float2 up[4];
    #pragma unroll
    for (int i = 0; i < 4; i++) {
        int p = t + i * 1024;
        float2 u = ((const float2*)Ub)[p];
        up[i] = u;
        int xi = (int)rintf(__fmul_rn(u.x, 1024.0f));  // rintf == jnp.round (half-even)
        int yi = (int)rintf(__fmul_rn(u.y, 1024.0f));
        xi = min(max(xi, 0), HH - 1);
        yi = min(max(yi, 0), WW - 1);
        lab[i] = Mb[xi * WW + yi];
        atomicAdd(&bEnd[lab[i]], 1);
    }
    __syncthreads();

    // ---- C: joint inclusive scan of bEnd & occA, then exclusive shift ----
    for (int stride = 1; stride < 1025; stride <<= 1) {
        int i1 = t + 1024;
        int a0 = 0, a1 = 0, c0 = 0, c1 = 0;
        if (t >= stride)               { a0 = bEnd[t - stride];  c0 = occA[t - stride]; }
        if (i1 < 1025 && i1 >= stride) { a1 = bEnd[i1 - stride]; c1 = occA[i1 - stride]; }
        __syncthreads();
        bEnd[t] += a0; occA[t] += c0;
        if (i1 < 1025) { bEnd[i1] += a1; occA[i1] += c1; }
        __syncthreads();
    }
    {
        int eA = (t == 0) ? 0 : bEnd[t - 1];
        int eB = (t == 0) ? 0 : occA[t - 1];
        int tA = bEnd[1023], tB = occA[1023];
        __syncthreads();
        bEnd[t] = eA; occA[t] = eB;
        if (t == 0) { bEnd[1024] = tA; occA[1024] = tB; }
        __syncthreads();
    }

    // ---- D: scatter ids + coords, bg0 init ----
    #pragma unroll
    for (int i = 0; i < 4; i++) {
        int p = t + i * 1024;
        int slot = atomicAdd(&bEnd[lab[i]], 1);
        ldsEnt[slot] = (unsigned short)p;
        bucketU[slot] = up[i];
        if (!((present[lab[i] >> 5] >> (lab[i] & 31)) & 1u))
            atomicOr(&bgbits[p >> 5], 1u << (p & 31));
    }
    {
        int slot = atomicAdd(&occA[k1], 1);
        occList[slot] = (unsigned short)t;
    }
    __syncthreads();

    // ---- 1a: per-label inside-match chains (thread t -> label t+1) ----
    float costPartial = 0.0f;
    {
        const int l = t + 1;
        const int os = occA[l - 1], oe = occA[l];
        for (int i = os + 1; i < oe; i++) {          // sort occurrences ascending
            unsigned short v = occList[i];
            int k = i - 1;
            while (k >= os && occList[k] > v) { occList[k + 1] = occList[k]; k--; }
            occList[k + 1] = v;
        }
        const int bs = bEnd[l - 1], be = bEnd[l];
        u64 cons = 0;                                 // consumed entries (eIdx<64)
        for (int o = os; o < oe; o++) {
            int j = occList[o];
            float2 v = ((const float2*)Vb)[j];
            u64 best = ~0ull;
            int avail = 0;
            for (int e = bs; e < be; e++) {
                int eIdx = e - bs;
                int p = ldsEnt[e];
                bool consumed;
                if (eIdx < 64) consumed = (cons >> eIdx) & 1ull;
                else {                                // exact fallback (never in practice)
                    consumed = false;
                    for (int o2 = os; o2 < o; o2++)
                        if ((int)matchU[occList[o2]] == p) { consumed = true; break; }
                }
                if (consumed) continue;
                avail++;
                float2 u = bucketU[e];
                float d = pdist(v.x, v.y, u.x, u.y);
                // pack (dist:32, p:12, eIdx:12): min => min dist, then min p
                u64 pk = ((u64)__float_as_uint(d) << 24) | ((u64)(unsigned)p << 12)
                         | (u64)(unsigned)eIdx;
                if (pk < best) best = pk;
            }
            if (avail > 0) {
                int eW = (int)(best & 0xFFFull);
                int pW = (int)((best >> 12) & 0xFFFull);
                costPartial = __fadd_rn(costPartial, __uint_as_float((unsigned)(best >> 24)));
                matchU[j] = (short)pW;
                if (eW < 64) cons |= 1ull << eW;
                evA[j + 1] = avail - 1;               // dump count at step j
            } else {
                matchU[j] = -2;                       // needs background match
            }
        }
    }
    __syncthreads();

    // ---- evA inclusive scan: evA[x] = # events of steps < x ----
    for (int stride = 1; stride < 1025; stride <<= 1) {
        int i1 = t + 1024;
        int a0 = 0, a1 = 0;
        if (t >= stride)               a0 = evA[t - stride];
        if (i1 < 1025 && i1 >= stride) a1 = evA[i1 - stride];
        __syncthreads();
        evA[t] += a0;
        if (i1 < 1025) evA[i1] += a1;
        __syncthreads();
    }

    // ---- bg-step list compaction (ascending j) ----
    {
        bool need = (matchU[t] == (short)-2);
        u64 m = __ballot(need);
        if ((t & 63) == 0) waveBase[t >> 6] = __popcll(m);
    }
    __syncthreads();
    if (t < 64) {
        int orig = (t < 16) ? waveBase[t] : 0;
        int v = orig;
        #pragma unroll
        for (int off = 1; off <= 8; off <<= 1) {
            int n = __shfl_up(v, off, 64);
            if (t >= off) v += n;
        }
        if (t < 16) waveBase[t] = v - orig;           // exclusive base
        if (t == 15) bgCntSh = v;                     // total
    }
    __syncthreads();
    {
        bool need = (matchU[t] == (short)-2);
        u64 m = __ballot(need);
        if (need) {
            int w = t >> 6, lane = t & 63;
            int rank = __popcll(m & ((1ull << lane) - 1ull));
            int idx = waveBase[w] + rank;
            if (idx < BGCAP) bgList[idx] = (unsigned short)t;
        }
    }

    // ---- 1b: replay, emit dump events (j-sorted by construction) ----
    {
        const int l = t + 1;
        const int os = occA[l - 1], oe = occA[l];
        const int bs = bEnd[l - 1], be = bEnd[l];
        u64 cons = 0;
        for (int o = os; o < oe; o++) {
            int j = occList[o];
            int u = matchU[j];
            if (u < 0) continue;
            int w = evA[j];
            for (int e = bs; e < be; e++) {
                int eIdx = e - bs;
                int p = ldsEnt[e];
                bool consumed;
                if (eIdx < 64) consumed = (cons >> eIdx) & 1ull;
                else {
                    consumed = false;
                    for (int o2 = os; o2 < o; o2++)
                        if ((int)matchU[occList[o2]] == p) { consumed = true; break; }
                }
                if (consumed) continue;
                if (p == u) { if (eIdx < 64) cons |= 1ull << eIdx; }
                else {
                    if (w < EVCAP_LDS) evPool[w] = (unsigned short)p;
                    else if (w - EVCAP_LDS < evCapG) evGlobB[w - EVCAP_LDS] = (unsigned short)p;
                    ++w;
                }
            }
        }
    }
    __syncthreads();

    // ---- stage V into LDS (bucketU region is dead; evPool occupies first 20KB) ----
    ldsV[t] = ((const float2*)Vb)[t];
    __syncthreads();

    // ---- 2: bg matches, full block per step, 2 barriers/step ----
    float bgCost = 0.0f;
    {
        const int bgCnt = min(bgCntSh, BGCAP);
        int appliedW = 0;
        bool havePending = false;
        int pendJs = 0;
        for (int s = 0; s <= bgCnt; ++s) {
            if (t < 64) {
                if (havePending) {                    // finalize step s-1
                    u64 v2 = (t < 16) ? waveMin[t] : ~0ull;
                    #pragma unroll
                    for (int off = 8; off >= 1; off >>= 1) {
                        u64 o = __shfl_xor(v2, off, 64);
                        if (o < v2) v2 = o;
                    }
                    if (t == 0) {
                        if (v2 != ~0ull) {
                            int u = (int)(v2 & 0xFFFFFFFFull);
                            matchU[pendJs] = (short)u;
                            atomicAnd(&bgbits[u >> 5], ~(1u << (u & 31)));
                            bgCost = __fadd_rn(bgCost, __uint_as_float((unsigned)(v2 >> 32)));
                        } else {
                            matchU[pendJs] = -1;
                        }
                    }
                }
                if (s < bgCnt) {                      // apply dump events for step s
                    int js = bgList[s];
                    int target = evA[js];
                    for (int base = appliedW; base < target; base += 64) {
                        int idx = base + t;
                        if (idx < target) {
                            int p = (idx < EVCAP_LDS) ? (int)evPool[idx]
                                                      : (int)evGlobB[idx - EVCAP_LDS];
                            atomicOr(&bgbits[p >> 5], 1u << (p & 31));
                        }
                    }
                    appliedW = target;
                }
            }
            __syncthreads();
            if (s < bgCnt) {                          // all threads: dist + reduce
                int js = bgList[s];
                float2 v = ldsV[js];
                u64 best = ~0ull;
                #pragma unroll
                for (int i = 0; i < 4; ++i) {
                    int p = t + i * 1024;
                    if ((bgbits[p >> 5] >> (p & 31)) & 1u) {
                        float d = pdist(v.x, v.y, up[i].x, up[i].y);
                        u64 pk = ((u64)__float_as_uint(d) << 32) | (unsigned)p;
                        if (pk < best) best = pk;
                    }
                }
                #pragma unroll
                for (int off = 32; off >= 1; off >>= 1) {
                    u64 o = __shfl_xor(best, off, 64);
                    if (o < best) best = o;
                }
                if ((t & 63) == 0) waveMin[t >> 6] = best;
                havePending = true;
                pendJs = js;
            } else {
                havePending = false;
            }
            __syncthreads();
        }
    }

    // ---- epilogue: cost reduction + outputs ----
    {
        float cp = costPartial;
        #pragma unroll
        for (int off = 32; off >= 1; off >>= 1) cp += __shfl_xor(cp, off, 64);
        if ((t & 63) == 0) waveCost[t >> 6] = cp;
    }
    __syncthreads();
    if (t == 0) {
        float tot = bgCost;
        for (int i = 0; i < 16; ++i) tot = __fadd_rn(tot, waveCost[i]);
        out[(size_t)2 * B * NGT + b] = tot;
    }
    {
        int u = matchU[t];
        out[(size_t)b * NGT + t] = (float)u;
        out[(size_t)B * NGT + (size_t)b * NGT + t] = (u >= 0) ? (float)t : -1.0f;
    }
}

extern "C" void kernel_launch(void* const* d_in, const int* in_sizes, int n_in,
                              void* d_out, int out_size, void* d_ws, size_t ws_size,
                              hipStream_t stream) {
    const float* pred   = (const float*)d_in[0];
    const float* coords = (const float*)d_in[1];
    const int*   keys   = (const int*)d_in[2];
    const int*   masks  = (const int*)d_in[3];
    float* out = (float*)d_out;
    int B = in_sizes[2] / NGT;   // 8
    int evCapG = (int)((ws_size / (size_t)B) / sizeof(unsigned short));
    matcher_kernel<<<B, 1024, 0, stream>>>(pred, coords, keys, masks, out,
                                           (unsigned short*)d_ws, evCapG, B);
}

// Round 4
// 191.789 us; speedup vs baseline: 6.7697x; 1.2171x over previous
//
#include <hip/hip_runtime.h>
#include <stdint.h>

// Problem constants: B=8, P=4096, N=1024, H=W=1024, labels 0..1024
#define PPTS 4096
#define NGT  1024
#define HH   1024
#define WW   1024
#define EVCAP_LDS 3400   // LDS event pool entries (E[total dumps] ~ 2600); global spill beyond
#define BGCAP 192        // max bg steps (E[m] ~ 65, sd ~10)

typedef unsigned long long u64;

__device__ __forceinline__ float pdist(float vx, float vy, float ux, float uy) {
    float dx = __fsub_rn(vx, ux);
    float dy = __fsub_rn(vy, uy);
    return __fsqrt_rn(__fadd_rn(__fmul_rn(dx, dx), __fmul_rn(dy, dy)));
}

// One block per batch.
//  A-D : stage U, label points, counting-sort into per-label buckets (2-barrier
//        joint scan), key-occurrence lists, bg0 bitmask.
//  1a  : one thread per label runs that label's inside-match chain.
//  1b  : replay, emit dump events j-sorted into evPool (+global spill).
//  2b  : SPECULATIVE bg argmins: one wave per bg step over its monotone base
//        set (bg0List ++ evPool prefix) — no barriers, 16-way parallel.
//  2c  : if all speculative winners distinct -> parallel commit (exact);
//        else single-wave sequential walk with O(1) validity bit-checks.
__global__ __launch_bounds__(1024) void matcher_kernel(
    const float* __restrict__ pred,    // [B,P,2]
    const float* __restrict__ coords,  // [B,N,2]
    const int*   __restrict__ keys,    // [B,N]
    const int*   __restrict__ masks,   // [B,H,W]
    float* __restrict__ out,           // [B*N src][B*N tgt][B total]
    unsigned short* __restrict__ evGlobAll, int evCapG, int B)
{
    __shared__ float2 ldsU[PPTS];                 // 32768, alive whole kernel
    __shared__ __align__(8) char regionA[8192];   // ldsEnt (<=1b) -> bg0List (>=2)
    __shared__ __align__(8) char regionB[8200];   // bEnd+occA (<=1b) -> vSteps+specWin
    __shared__ u64            waveMin[16];        //   128
    __shared__ int            evAx[1025];         //  4100 exclusive event offsets
    __shared__ unsigned short occList[NGT];       //  2048
    __shared__ short          matchU[NGT];        //  2048
    __shared__ unsigned       bgbits[PPTS / 32];  //   512
    __shared__ unsigned       present[33];        //   132
    __shared__ unsigned short bgListSh[BGCAP];    //   384
    __shared__ unsigned short evPool[EVCAP_LDS];  //  6800
    __shared__ int            waveBase[16];       //    64
    __shared__ float          waveCost[16];       //    64
    __shared__ int            scal[4];            // 0:bgCnt 1:nBg0 2:dupFlag

    unsigned short* ldsEnt  = (unsigned short*)regionA;
    unsigned short* bg0List = (unsigned short*)regionA;
    int* bEnd = (int*)regionB;
    int* occA = (int*)(regionB + 4100);
    float2* vSteps = (float2*)regionB;                 // BGCAP*8 = 1536
    u64*    specWin = (u64*)(regionB + 1536);          // BGCAP*8 = 1536

    const int b = blockIdx.x;
    const int t = threadIdx.x;
    const int lane = t & 63, wv = t >> 6;
    const float* Ub = pred   + (size_t)b * PPTS * 2;
    const float* Vb = coords + (size_t)b * NGT * 2;
    const int*   Kb = keys   + (size_t)b * NGT;
    const int*   Mb = masks  + (size_t)b * HH * WW;
    unsigned short* evGlobB = evGlobAll + (size_t)b * (size_t)evCapG;

    // ---- A: zero ----
    bEnd[t] = 0; occA[t] = 0; evAx[t] = 0;
    if (t == 0) { bEnd[1024] = 0; occA[1024] = 0; evAx[1024] = 0;
                  scal[0] = 0; scal[1] = 0; scal[2] = 0; }
    if (t < PPTS / 32) bgbits[t] = 0;
    if (t < 33) present[t] = 0;
    __syncthreads();

    // ---- B: histograms + mask gather; coords of owned points stay in regs ----
    const int k1 = Kb[t] + 1;                     // label of step j=t, in [1,1024]
    atomicOr(&present[k1 >> 5], 1u << (k1 & 31));
    atomicAdd(&occA[k1], 1);
    int lab[4]; float2 up[4];
    #pragma unroll
    for (int i = 0; i < 4; i++) {
        int p = t + i * 1024;
        float2 u = ((const float2*)Ub)[p];
        up[i] = u;
        int xi = (int)rintf(__fmul_rn(u.x, 1024.0f));  // rintf == jnp.round (half-even)
        int yi = (int)rintf(__fmul_rn(u.y, 1024.0f));
        xi = min(max(xi, 0), HH - 1);
        yi = min(max(yi, 0), WW - 1);
        lab[i] = Mb[xi * WW + yi];
        ldsU[p] = u;
        atomicAdd(&bEnd[lab[i]], 1);
    }
    __syncthreads();

    // ---- C: joint EXCLUSIVE scan of bEnd & occA, 2 barriers (packed u64) ----
    {
        int a = bEnd[t], c = occA[t];
        u64 pk = ((u64)(unsigned)a << 32) | (unsigned)c;
        u64 inc = pk;
        #pragma unroll
        for (int off = 1; off < 64; off <<= 1) {
            u64 n = __shfl_up(inc, off, 64);
            if (lane >= off) inc += n;
        }
        if (lane == 63) waveMin[wv] = inc;
        __syncthreads();
        if (t < 16) {
            u64 v = waveMin[t], inc2 = v;
            #pragma unroll
            for (int off = 1; off < 16; off <<= 1) {
                u64 n = __shfl_up(inc2, off, 64);
                if (t >= off) inc2 += n;
            }
            waveMin[t] = inc2 - v;                // exclusive wave offset
        }
        __syncthreads();
        u64 excl = waveMin[wv] + inc - pk;
        int ea = (int)(excl >> 32), ec = (int)(excl & 0xFFFFFFFFu);
        bEnd[t] = ea; occA[t] = ec;
        if (t == 1023) { bEnd[1024] = ea + a; occA[1024] = ec + c; }
    }
    __syncthreads();

    // ---- D: scatter ids, occ lists, bg0 bitmask ----
    #pragma unroll
    for (int i = 0; i < 4; i++) {
        int p = t + i * 1024;
        int slot = atomicAdd(&bEnd[lab[i]], 1);
        ldsEnt[slot] = (unsigned short)p;
        if (!((present[lab[i] >> 5] >> (lab[i] & 31)) & 1u))
            atomicOr(&bgbits[p >> 5], 1u << (p & 31));
    }
    {
        int slot = atomicAdd(&occA[k1], 1);
        occList[slot] = (unsigned short)t;
    }
    __syncthreads();

    // ---- 1a: per-label inside-match chains (thread t -> label t+1) ----
    float costPartial = 0.0f;
    {
        const int l = t + 1;
        const int os = occA[l - 1], oe = occA[l];
        for (int i = os + 1; i < oe; i++) {          // sort occurrences ascending
            unsigned short v = occList[i];
            int k = i - 1;
            while (k >= os && occList[k] > v) { occList[k + 1] = occList[k]; k--; }
            occList[k + 1] = v;
        }
        const int bs = bEnd[l - 1], be = bEnd[l];
        u64 cons = 0;
        for (int o = os; o < oe; o++) {
            int j = occList[o];
            float2 v = ((const float2*)Vb)[j];
            u64 best = ~0ull;
            int avail = 0;
            for (int e = bs; e < be; e++) {
                int eIdx = e - bs;
                int p = ldsEnt[e];
                bool consd;
                if (eIdx < 64) consd = (cons >> eIdx) & 1ull;
                else {
                    consd = false;
                    for (int o2 = os; o2 < o; o2++)
                        if ((int)matchU[occList[o2]] == p) { consd = true; break; }
                }
                if (consd) continue;
                avail++;
                float2 u = ldsU[p];
                float d = pdist(v.x, v.y, u.x, u.y);
                u64 pk = ((u64)__float_as_uint(d) << 24) | ((u64)(unsigned)p << 12)
                         | (u64)(unsigned)eIdx;
                if (pk < best) best = pk;
            }
            if (avail > 0) {
                int eW = (int)(best & 0xFFFull);
                int pW = (int)((best >> 12) & 0xFFFull);
                costPartial = __fadd_rn(costPartial, __uint_as_float((unsigned)(best >> 24)));
                matchU[j] = (short)pW;
                if (eW < 64) cons |= 1ull << eW;
                evAx[j] = avail - 1;                 // dump count at step j
            } else {
                matchU[j] = -2;
            }
        }
    }
    __syncthreads();

    // ---- evAx EXCLUSIVE scan (2 barriers) ----
    {
        int v = evAx[t], inc = v;
        #pragma unroll
        for (int off = 1; off < 64; off <<= 1) {
            int n = __shfl_up(inc, off, 64);
            if (lane >= off) inc += n;
        }
        if (lane == 63) waveBase[wv] = inc;
        __syncthreads();
        if (t < 16) {
            int s0 = waveBase[t], inc2 = s0;
            #pragma unroll
            for (int off = 1; off < 16; off <<= 1) {
                int n = __shfl_up(inc2, off, 64);
                if (t >= off) inc2 += n;
            }
            waveBase[t] = inc2 - s0;
        }
        __syncthreads();
        evAx[t] = waveBase[wv] + inc - v;
    }
    __syncthreads();

    // ---- bg-step list compaction (ascending j) ----
    {
        bool need = (matchU[t] == (short)-2);
        u64 m = __ballot(need);
        if (lane == 0) waveBase[wv] = __popcll(m);
    }
    __syncthreads();
    if (t < 64) {
        int orig = (t < 16) ? waveBase[t] : 0;
        int v = orig;
        #pragma unroll
        for (int off = 1; off <= 8; off <<= 1) {
            int n = __shfl_up(v, off, 64);
            if (t >= off) v += n;
        }
        if (t < 16) waveBase[t] = v - orig;
        if (t == 15) scal[0] = v;
    }
    __syncthreads();
    {
        bool need = (matchU[t] == (short)-2);
        u64 m = __ballot(need);
        if (need) {
            int rank = __popcll(m & ((1ull << lane) - 1ull));
            int idx = waveBase[wv] + rank;
            if (idx < BGCAP) bgListSh[idx] = (unsigned short)t;
        }
    }

    // ---- 1b: replay, emit dump events (j-sorted by construction) ----
    {
        const int l = t + 1;
        const int os = occA[l - 1], oe = occA[l];
        const int bs = bEnd[l - 1], be = bEnd[l];
        u64 cons = 0;
        for (int o = os; o < oe; o++) {
            int j = occList[o];
            int u = matchU[j];
            if (u < 0) continue;
            int w2 = evAx[j];
            for (int e = bs; e < be; e++) {
                int eIdx = e - bs;
                int p = ldsEnt[e];
                bool consd;
                if (eIdx < 64) consd = (cons >> eIdx) & 1ull;
                else {
                    consd = false;
                    for (int o2 = os; o2 < o; o2++)
                        if ((int)matchU[occList[o2]] == p) { consd = true; break; }
                }
                if (consd) continue;
                if (p == u) { if (eIdx < 64) cons |= 1ull << eIdx; }
                else {
                    if (w2 < EVCAP_LDS) evPool[w2] = (unsigned short)p;
                    else if (w2 - EVCAP_LDS < evCapG) evGlobB[w2 - EVCAP_LDS] = (unsigned short)p;
                    ++w2;
                }
            }
        }
    }
    __syncthreads();

    // ---- bg0 list build (regionA freed) + vSteps staging ----
    const int bgCnt = min(scal[0], BGCAP);
    #pragma unroll
    for (int i = 0; i < 4; i++) {
        int p = t + i * 1024;
        bool inBg = (bgbits[p >> 5] >> (p & 31)) & 1u;
        u64 m = __ballot(inBg);
        int base = 0;
        if (lane == 0 && m) base = atomicAdd(&scal[1], __popcll(m));
        base = __shfl(base, 0, 64);
        if (inBg) {
            int rank = __popcll(m & ((1ull << lane) - 1ull));
            bg0List[base + rank] = (unsigned short)p;
        }
    }
    if (t < bgCnt) vSteps[t] = ((const float2*)Vb)[bgListSh[t]];
    __syncthreads();
    const int nBg0 = scal[1];

    // ---- 2b: speculative argmins, one wave per bg step, no barriers ----
    for (int s = wv; s < bgCnt; s += 16) {
        int js = bgListSh[s];
        float2 v = vSteps[s];
        int cnt = nBg0 + evAx[js];
        u64 best = ~0ull;
        for (int i = lane; i < cnt; i += 64) {
            int p;
            if (i < nBg0) p = bg0List[i];
            else {
                int ei = i - nBg0;
                p = (ei < EVCAP_LDS) ? (int)evPool[ei] : (int)evGlobB[ei - EVCAP_LDS];
            }
            float2 u = ldsU[p];
            float d = pdist(v.x, v.y, u.x, u.y);
            u64 pk = ((u64)__float_as_uint(d) << 32) | (unsigned)p;
            if (pk < best) best = pk;
        }
        #pragma unroll
        for (int off = 32; off >= 1; off >>= 1) {
            u64 o = __shfl_xor(best, off, 64);
            if (o < best) best = o;
        }
        if (lane == 0) specWin[s] = best;
    }
    __syncthreads();

    // ---- 2c: duplicate-winner check; fast parallel commit or sequential walk ----
    if (t < bgCnt) {
        u64 w0 = specWin[t];
        if (w0 != ~0ull) {
            unsigned myp = (unsigned)(w0 & 0xFFFFFFFFull);
            for (int s2 = 0; s2 < t; s2++) {
                u64 ws = specWin[s2];
                if (ws != ~0ull && (unsigned)(ws & 0xFFFFFFFFull) == myp) { scal[2] = 1; break; }
            }
        }
    }
    __syncthreads();
    float bgCost = 0.0f;
    if (scal[2] == 0) {
        // all winners distinct -> every speculative winner is exact (present in
        // the actual set, which is a subset of its base set)
        if (t < bgCnt) {
            int js = bgListSh[t];
            u64 w0 = specWin[t];
            if (w0 == ~0ull) matchU[js] = -1;
            else {
                matchU[js] = (short)(w0 & 0xFFFull);
                costPartial = __fadd_rn(costPartial, __uint_as_float((unsigned)(w0 >> 32)));
            }
        }
    } else if (t < 64) {
        // sequential walk: apply events, O(1) validity check, rare recompute
        int applied = 0;
        for (int s = 0; s < bgCnt; s++) {
            int js = bgListSh[s];
            int target = evAx[js];
            for (int base = applied; base < target; base += 64) {
                int idx = base + t;
                if (idx < target) {
                    int p = (idx < EVCAP_LDS) ? (int)evPool[idx]
                                              : (int)evGlobB[idx - EVCAP_LDS];
                    atomicOr(&bgbits[p >> 5], 1u << (p & 31));
                }
            }
            applied = target;
            __threadfence_block();
            u64 w0 = specWin[s];
            if (w0 == ~0ull) {
                if (t == 0) matchU[js] = -1;
            } else {
                int u = (int)(w0 & 0xFFFFFFFFull);
                bool setb = (bgbits[u >> 5] >> (u & 31)) & 1u;
                if (setb) {
                    if (t == 0) {
                        matchU[js] = (short)u;
                        atomicAnd(&bgbits[u >> 5], ~(1u << (u & 31)));
                        bgCost = __fadd_rn(bgCost, __uint_as_float((unsigned)(w0 >> 32)));
                    }
                } else {
                    float2 v = vSteps[s];
                    u64 best = ~0ull;
                    #pragma unroll
                    for (int i = 0; i < 2; i++) {
                        int wi = t * 2 + i;
                        unsigned bits = bgbits[wi];
                        int pb = wi << 5;
                        while (bits) {
                            int bpos = __builtin_ctz(bits);
                            bits &= bits - 1;
                            int p = pb + bpos;
                            float2 uu = ldsU[p];
                            float d = pdist(v.x, v.y, uu.x, uu.y);
                            u64 pk = ((u64)__float_as_uint(d) << 32) | (unsigned)p;
                            if (pk < best) best = pk;
                        }
                    }
                    #pragma unroll
                    for (int off = 32; off >= 1; off >>= 1) {
                        u64 o = __shfl_xor(best, off, 64);
                        if (o < best) best = o;
                    }
                    if (t == 0) {
                        if (best != ~0ull) {
                            int u2 = (int)(best & 0xFFFFFFFFull);
                            matchU[js] = (short)u2;
                            atomicAnd(&bgbits[u2 >> 5], ~(1u << (u2 & 31)));
                            bgCost = __fadd_rn(bgCost, __uint_as_float((unsigned)(best >> 32)));
                        } else matchU[js] = -1;
                    }
                }
                __threadfence_block();
            }
        }
    }
    __syncthreads();

    // ---- epilogue: cost reduction + outputs ----
    {
        float cp = costPartial;
        #pragma unroll
        for (int off = 32; off >= 1; off >>= 1) cp += __shfl_xor(cp, off, 64);
        if (lane == 0) waveCost[wv] = cp;
    }
    __syncthreads();
    if (t == 0) {
        float tot = bgCost;
        for (int i = 0; i < 16; ++i) tot = __fadd_rn(tot, waveCost[i]);
        out[(size_t)2 * B * NGT + b] = tot;
    }
    {
        int u = matchU[t];
        out[(size_t)b * NGT + t] = (float)u;
        out[(size_t)B * NGT + (size_t)b * NGT + t] = (u >= 0) ? (float)t : -1.0f;
    }
}

extern "C" void kernel_launch(void* const* d_in, const int* in_sizes, int n_in,
                              void* d_out, int out_size, void* d_ws, size_t ws_size,
                              hipStream_t stream) {
    const float* pred   = (const float*)d_in[0];
    const float* coords = (const float*)d_in[1];
    const int*   keys   = (const int*)d_in[2];
    const int*   masks  = (const int*)d_in[3];
    float* out = (float*)d_out;
    int B = in_sizes[2] / NGT;   // 8
    int evCapG = (int)((ws_size / (size_t)B) / sizeof(unsigned short));
    matcher_kernel<<<B, 1024, 0, stream>>>(pred, coords, keys, masks, out,
                                           (unsigned short*)d_ws, evCapG, B);
}